// Round 3
// baseline (246.014 us; speedup 1.0000x reference)
//
#include <hip/hip_runtime.h>

// Problem constants (n=4, L=8192, h=8, e=64, fp32)
#define N_      4
#define L_      8192
#define H_      8
#define E_      64
#define NH_     (N_ * H_)          // 32
#define STRIDE_ (H_ * E_)          // 512 floats between consecutive rows
#define SPLIT_  32                 // s-split for phase 1
#define RPB_    (L_ / SPLIT_)      // 256 rows per block
#define RPW_    (RPB_ / 2)         // 128 rows per wave (2 waves/block)
#define P_      4                  // global prefetch depth (rows)

// Final ws layout: KV[NH_][64][64], then ksum[NH_][64]
#define WS_KV_FLOATS    ((size_t)NH_ * E_ * E_)
#define WS_TOTAL_FLOATS (WS_KV_FLOATS + (size_t)NH_ * E_)
// Partial buffers (no-atomic path) appended after:
#define PKV_OFF   WS_TOTAL_FLOATS
#define PKV_FLOATS ((size_t)NH_ * SPLIT_ * E_ * E_)
#define PKS_OFF   (PKV_OFF + PKV_FLOATS)
#define PKS_FLOATS ((size_t)NH_ * SPLIT_ * E_)
#define WS_NEED_BYTES ((PKS_OFF + PKS_FLOATS) * sizeof(float))

__device__ __forceinline__ float featmap(float x) {
    float xs = x * 0.35355339059327373f;     // * 64^-0.25
    return xs > 0.0f ? xs + 1.0f : __expf(xs);
}

// ---------------------------------------------------------------------------
// Phase 1: per-wave streaming KV accumulation. lane = m; acc[d] in 64 VGPRs.
// Per row: 2 coalesced dword loads, featmap, kf row -> per-wave LDS buffer,
// 16 uniform (broadcast) ds_read_b128 + 64 FMA. No __syncthreads in the loop.
// Epilogue: 2 waves combine via LDS, then plain coalesced partial store
// (ATOMIC=false) or global atomicAdd fallback (ATOMIC=true).
// ---------------------------------------------------------------------------
template <bool ATOMIC>
__global__ __launch_bounds__(128) void la_kv_partial(
    const float* __restrict__ keys, const float* __restrict__ values,
    float* __restrict__ pkv, float* __restrict__ pks, float* __restrict__ ws)
{
    const int blk   = blockIdx.x;           // nh*SPLIT_ + chunk
    const int nh    = blk / SPLIT_;
    const int chunk = blk % SPLIT_;
    const int n = nh / H_, h = nh % H_;
    const int tid  = threadIdx.x;
    const int wave = tid >> 6;
    const int lane = tid & 63;

    __shared__ float kbuf[2][2][E_];        // [wave][dbuf][64] kf broadcast
    __shared__ float red[2][E_ * E_];       // per-wave 64x64 partials (32 KB)
    __shared__ float ksr[2][E_];

    float acc[E_];
    #pragma unroll
    for (int d = 0; d < E_; ++d) acc[d] = 0.f;
    float ksum = 0.f;

    const size_t base = ((size_t)n * L_ * H_ + h) * E_ + lane;
    const int r0 = chunk * RPB_ + wave * RPW_;

    float kr[P_], vr[P_];
    #pragma unroll
    for (int p = 0; p < P_; ++p) {
        const size_t o = base + (size_t)(r0 + p) * STRIDE_;
        kr[p] = keys[o];
        vr[p] = values[o];
    }

    #define ROW_BODY(P_IDX, BUFSEL, PREFETCH_ROW)                              \
    {                                                                          \
        const float kf = featmap(kr[P_IDX]);                                   \
        const float vv = vr[P_IDX];                                            \
        ksum += kf;                                                            \
        kbuf[wave][BUFSEL][lane] = kf;                                         \
        if (PREFETCH_ROW >= 0) {                                               \
            const size_t o = base + (size_t)(PREFETCH_ROW) * STRIDE_;          \
            kr[P_IDX] = keys[o];                                               \
            vr[P_IDX] = values[o];                                             \
        }                                                                      \
        _Pragma("unroll")                                                      \
        for (int d0 = 0; d0 < E_; d0 += 4) {                                   \
            float4 k4 = *reinterpret_cast<const float4*>(&kbuf[wave][BUFSEL][d0]); \
            acc[d0 + 0] = fmaf(k4.x, vv, acc[d0 + 0]);                         \
            acc[d0 + 1] = fmaf(k4.y, vv, acc[d0 + 1]);                         \
            acc[d0 + 2] = fmaf(k4.z, vv, acc[d0 + 2]);                         \
            acc[d0 + 3] = fmaf(k4.w, vv, acc[d0 + 3]);                         \
        }                                                                      \
    }

    // Main loop: rows in groups of P_=4, always prefetching P_ ahead.
    for (int rr = 0; rr < RPW_ - P_; rr += P_) {
        ROW_BODY(0, 0, r0 + rr + 0 + P_);
        ROW_BODY(1, 1, r0 + rr + 1 + P_);
        ROW_BODY(2, 0, r0 + rr + 2 + P_);
        ROW_BODY(3, 1, r0 + rr + 3 + P_);
    }
    // Last group: no prefetch.
    ROW_BODY(0, 0, -1);
    ROW_BODY(1, 1, -1);
    ROW_BODY(2, 0, -1);
    ROW_BODY(3, 1, -1);
    #undef ROW_BODY

    // Cross-wave combine: each wave writes its partial (2-way bank alias: free)
    #pragma unroll
    for (int d = 0; d < E_; ++d) red[wave][d * E_ + lane] = acc[d];
    ksr[wave][lane] = ksum;
    __syncthreads();

    if (!ATOMIC) {
        float* dst = pkv + (size_t)blk * (E_ * E_);
        #pragma unroll
        for (int i = 0; i < 8; ++i) {
            const int o = tid * 4 + i * 512;
            float4 a = *reinterpret_cast<const float4*>(&red[0][o]);
            float4 b = *reinterpret_cast<const float4*>(&red[1][o]);
            a.x += b.x; a.y += b.y; a.z += b.z; a.w += b.w;
            *reinterpret_cast<float4*>(&dst[o]) = a;
        }
        if (tid < E_) pks[(size_t)blk * E_ + tid] = ksr[0][tid] + ksr[1][tid];
    } else {
        float* W = ws + (size_t)nh * (E_ * E_);
        #pragma unroll
        for (int i = 0; i < 8; ++i) {
            const int o = tid * 4 + i * 512;
            float4 a = *reinterpret_cast<const float4*>(&red[0][o]);
            float4 b = *reinterpret_cast<const float4*>(&red[1][o]);
            atomicAdd(&W[o + 0], a.x + b.x);
            atomicAdd(&W[o + 1], a.y + b.y);
            atomicAdd(&W[o + 2], a.z + b.z);
            atomicAdd(&W[o + 3], a.w + b.w);
        }
        if (tid < E_)
            atomicAdd(&ws[WS_KV_FLOATS + (size_t)nh * E_ + tid],
                      ksr[0][tid] + ksr[1][tid]);
    }
}

// ---------------------------------------------------------------------------
// Reduce: KV[nh][e] = sum_c pkv[nh*SPLIT_+c][e]; same for ksum.
// Grid 512 blocks x 256 threads; coalesced stride-16KB reads, MLP 32.
// ---------------------------------------------------------------------------
__global__ __launch_bounds__(256) void la_reduce(
    const float* __restrict__ pkv, const float* __restrict__ pks,
    float* __restrict__ ws)
{
    const int b  = blockIdx.x;            // 32 nh x 16 slices
    const int nh = b >> 4;
    const int e  = (b & 15) * 256 + threadIdx.x;
    const float* src = pkv + ((size_t)nh * SPLIT_) * (E_ * E_) + e;
    float s = 0.f;
    #pragma unroll
    for (int c = 0; c < SPLIT_; ++c) s += src[(size_t)c * (E_ * E_)];
    ws[(size_t)nh * (E_ * E_) + e] = s;

    if ((b & 15) == 0 && threadIdx.x < E_) {
        const float* sk = pks + (size_t)nh * SPLIT_ * E_ + threadIdx.x;
        float t = 0.f;
        #pragma unroll
        for (int c = 0; c < SPLIT_; ++c) t += sk[c * E_];
        ws[WS_KV_FLOATS + (size_t)nh * E_ + threadIdx.x] = t;
    }
}

// ---------------------------------------------------------------------------
// Phase 2: out[l][m] = z * sum_d qf[d] * W[d][m]. lane = m; KV column in VGPRs.
// ---------------------------------------------------------------------------
__global__ __launch_bounds__(256) void la_phase2(
    const float* __restrict__ queries, const float* __restrict__ ws,
    float* __restrict__ out)
{
    const int blk  = blockIdx.x;
    const int nh   = blk >> 6;        // 64 blocks per (n,h)
    const int tile = blk & 63;
    const int n = nh / H_, h = nh % H_;
    const int t = threadIdx.x;
    const int w = t >> 6, lane = t & 63;

    const float* W = ws + (size_t)nh * (E_ * E_);
    float kv[E_];
    #pragma unroll
    for (int d = 0; d < E_; ++d) kv[d] = W[d * E_ + lane];
    const float ksum_l = ws[WS_KV_FLOATS + (size_t)nh * E_ + lane];

    __shared__ float qbuf[4][E_];

    const size_t base = ((size_t)n * L_ * H_ + h) * E_;
    const int row0 = tile * 128 + w * 32;

    size_t off = base + (size_t)row0 * STRIDE_ + lane;
    float q_raw = queries[off];

    for (int r = 0; r < 32; ++r) {
        const size_t off_cur = off;
        float q_next = 0.f;
        if (r < 31) {                      // prefetch next row
            off += STRIDE_;
            q_next = queries[off];
        }
        const float qf = featmap(q_raw);

        // z = 1 / (sum_d qf[d]*ksum[d] + eps)
        float zp = qf * ksum_l;
        #pragma unroll
        for (int sh = 32; sh >= 1; sh >>= 1) zp += __shfl_xor(zp, sh);
        const float z = 1.0f / (zp + 1e-6f);

        qbuf[w][lane] = qf;
        __builtin_amdgcn_wave_barrier();

        float acc = 0.f;
        #pragma unroll
        for (int d0 = 0; d0 < E_; d0 += 4) {
            float4 q4 = *reinterpret_cast<const float4*>(&qbuf[w][d0]);
            acc = fmaf(q4.x, kv[d0 + 0], acc);
            acc = fmaf(q4.y, kv[d0 + 1], acc);
            acc = fmaf(q4.z, kv[d0 + 2], acc);
            acc = fmaf(q4.w, kv[d0 + 3], acc);
        }
        __builtin_amdgcn_wave_barrier();

        out[off_cur] = acc * z;
        q_raw = q_next;
    }
}

extern "C" void kernel_launch(void* const* d_in, const int* in_sizes, int n_in,
                              void* d_out, int out_size, void* d_ws, size_t ws_size,
                              hipStream_t stream) {
    (void)in_sizes; (void)n_in; (void)out_size;
    const float* q = (const float*)d_in[0];
    const float* k = (const float*)d_in[1];
    const float* v = (const float*)d_in[2];
    float* outp = (float*)d_out;
    float* ws   = (float*)d_ws;

    if (ws_size >= WS_NEED_BYTES) {
        // Preferred path: no atomics, no memset.
        float* pkv = ws + PKV_OFF;
        float* pks = ws + PKS_OFF;
        la_kv_partial<false><<<NH_ * SPLIT_, 128, 0, stream>>>(k, v, pkv, pks, ws);
        la_reduce<<<NH_ * 16, 256, 0, stream>>>(pkv, pks, ws);
    } else {
        // Fallback: atomic accumulation directly into ws.
        hipMemsetAsync(d_ws, 0, WS_TOTAL_FLOATS * sizeof(float), stream);
        la_kv_partial<true><<<NH_ * SPLIT_, 128, 0, stream>>>(k, v, nullptr, nullptr, ws);
    }
    la_phase2<<<NH_ * 64, 256, 0, stream>>>(q, ws, outp);
}

// Round 4
// 66.214 us; speedup vs baseline: 3.7155x; 3.7155x over previous
//
#include <hip/hip_runtime.h>

// n=4, L=8192, h=8, e=64, fp32 in/out
#define N_      4
#define L_      8192
#define H_      8
#define E_      64
#define NH_     (N_ * H_)
#define STRIDE_ (H_ * E_)          // 512 floats between rows
#define SPLIT_  32                 // s-split for phase 1
#define RPB_    (L_ / SPLIT_)      // 256 rows per p1 block
#define NKB_    (RPB_ / 32)        // 8 staged K-blocks of 32 rows
#define PITCH_  40                 // bf16 LDS pitch (80 B: 16B-aligned, 8-slot spread)

// ws layout (floats): pkv[1024][4096] | pks[1024][64] | kvt(bf16)[32][4096] | ksum[32][64]
#define PKV_FLOATS ((size_t)NH_ * SPLIT_ * E_ * E_)
#define PKS_FLOATS ((size_t)NH_ * SPLIT_ * E_)
#define KVT_FLOATS ((size_t)NH_ * E_ * E_ / 2)     // bf16 stored in float-sized area
#define PKS_OFF  PKV_FLOATS
#define KVT_OFF  (PKV_FLOATS + PKS_FLOATS)
#define KSUM_OFF (KVT_OFF + KVT_FLOATS)

typedef short bf16x8 __attribute__((ext_vector_type(8)));
typedef float f32x16 __attribute__((ext_vector_type(16)));

__device__ __forceinline__ float featmap(float x) {
    float xs = x * 0.35355339059327373f;   // * 64^-0.25
    return xs > 0.0f ? xs + 1.0f : __expf(xs);
}
__device__ __forceinline__ unsigned short f2bf(float f) {   // RNE f32->bf16
    union { float f; unsigned u; } c{f};
    unsigned r = c.u + 0x7FFFu + ((c.u >> 16) & 1u);
    return (unsigned short)(r >> 16);
}
__device__ __forceinline__ unsigned pack2(float lo, float hi) {
    return (unsigned)f2bf(lo) | ((unsigned)f2bf(hi) << 16);
}

// ---------------------------------------------------------------------------
// Phase 1: KV_partial[d][m] = sum_s kf[s,d]*v[s,m] via bf16 MFMA 32x32x16.
// 256 thr = 4 waves (2x2 tiles of 32x32). Stage 32 s-rows per K-block:
// thread (p=t>>4 s-pair, d4=t&15 col-quad) loads coalesced f4 pairs, packs
// bf16 pairs into Kb/Vb[row][s] (pitch 40). Double-buffer, 1 barrier/K-block.
// ---------------------------------------------------------------------------
__global__ __launch_bounds__(256) void la_kv(
    const float* __restrict__ keys, const float* __restrict__ values,
    float* __restrict__ pkv, float* __restrict__ pks)
{
    const int blk = blockIdx.x;
    const int nh = blk / SPLIT_, chunk = blk % SPLIT_;
    const int n = nh / H_, h = nh % H_;
    const int t = threadIdx.x, l = t & 63;
    const int w = t >> 6, wd = w >> 1, wm = w & 1;
    const int d4 = t & 15, p = t >> 4;
    const int lm = l & 31, lh = l >> 5;

    __shared__ unsigned short Kb[2][E_][PITCH_];
    __shared__ unsigned short Vb[2][E_][PITCH_];

    f32x16 acc = {0,0,0,0,0,0,0,0,0,0,0,0,0,0,0,0};
    float sk0 = 0.f, sk1 = 0.f, sk2 = 0.f, sk3 = 0.f;

    const size_t base = (size_t)n * (L_ * H_ * E_) + (size_t)h * E_;
    const float* kp = keys   + base + (size_t)(chunk * RPB_ + 2 * p) * STRIDE_ + d4 * 4;
    const float* vp = values + base + (size_t)(chunk * RPB_ + 2 * p) * STRIDE_ + d4 * 4;

    float4 k0 = *(const float4*)kp;
    float4 k1 = *(const float4*)(kp + STRIDE_);
    float4 v0 = *(const float4*)vp;
    float4 v1 = *(const float4*)(vp + STRIDE_);

    for (int i = 0; i < NKB_; ++i) {
        const int buf = i & 1;
        float4 nk0, nk1, nv0, nv1;
        if (i + 1 < NKB_) {               // prefetch next K-block
            kp += 32 * STRIDE_; vp += 32 * STRIDE_;
            nk0 = *(const float4*)kp; nk1 = *(const float4*)(kp + STRIDE_);
            nv0 = *(const float4*)vp; nv1 = *(const float4*)(vp + STRIDE_);
        } else { nk0 = k0; nk1 = k1; nv0 = v0; nv1 = v1; }

        const float a0 = featmap(k0.x), a1 = featmap(k0.y),
                    a2 = featmap(k0.z), a3 = featmap(k0.w);
        const float b0 = featmap(k1.x), b1 = featmap(k1.y),
                    b2 = featmap(k1.z), b3 = featmap(k1.w);
        sk0 += a0 + b0; sk1 += a1 + b1; sk2 += a2 + b2; sk3 += a3 + b3;

        *(unsigned*)&Kb[buf][4 * d4 + 0][2 * p] = pack2(a0, b0);
        *(unsigned*)&Kb[buf][4 * d4 + 1][2 * p] = pack2(a1, b1);
        *(unsigned*)&Kb[buf][4 * d4 + 2][2 * p] = pack2(a2, b2);
        *(unsigned*)&Kb[buf][4 * d4 + 3][2 * p] = pack2(a3, b3);
        *(unsigned*)&Vb[buf][4 * d4 + 0][2 * p] = pack2(v0.x, v1.x);
        *(unsigned*)&Vb[buf][4 * d4 + 1][2 * p] = pack2(v0.y, v1.y);
        *(unsigned*)&Vb[buf][4 * d4 + 2][2 * p] = pack2(v0.z, v1.z);
        *(unsigned*)&Vb[buf][4 * d4 + 3][2 * p] = pack2(v0.w, v1.w);

        __syncthreads();   // tile visible; dbuf makes one barrier sufficient

        bf16x8 af0 = *(const bf16x8*)&Kb[buf][32 * wd + lm][8 * lh];
        bf16x8 bf0 = *(const bf16x8*)&Vb[buf][32 * wm + lm][8 * lh];
        acc = __builtin_amdgcn_mfma_f32_32x32x16_bf16(af0, bf0, acc, 0, 0, 0);
        bf16x8 af1 = *(const bf16x8*)&Kb[buf][32 * wd + lm][16 + 8 * lh];
        bf16x8 bf1 = *(const bf16x8*)&Vb[buf][32 * wm + lm][16 + 8 * lh];
        acc = __builtin_amdgcn_mfma_f32_32x32x16_bf16(af1, bf1, acc, 0, 0, 0);

        k0 = nk0; k1 = nk1; v0 = nv0; v1 = nv1;
    }

    // C/D layout (m74/m101 verified): col=lane&31, row=(reg&3)+8*(reg>>2)+4*(lane>>5)
    float* dst = pkv + (size_t)blk * (E_ * E_);
    #pragma unroll
    for (int r = 0; r < 16; ++r) {
        const int ro = (r & 3) + 8 * (r >> 2) + 4 * lh;
        dst[(32 * wd + ro) * E_ + 32 * wm + lm] = acc[r];
    }

    // ksum partials -> LDS (reuse Kb[0]) -> 64-thread reduce -> plain store
    __syncthreads();
    float* ksb = (float*)&Kb[0][0][0];     // [16][68] scratch, 4.3 KB
    *(float4*)&ksb[p * 68 + 4 * d4] = make_float4(sk0, sk1, sk2, sk3);
    __syncthreads();
    if (t < E_) {
        float ss = 0.f;
        #pragma unroll
        for (int pp = 0; pp < 16; ++pp) ss += ksb[pp * 68 + t];
        pks[(size_t)blk * E_ + t] = ss;
    }
}

// ---------------------------------------------------------------------------
// Reduce: KV[d][m] = sum_c pkv; emit KV^T as bf16 [m][d] (B-frag friendly)
// and ksum f32. 512 blocks x 256 thr.
// ---------------------------------------------------------------------------
__global__ __launch_bounds__(256) void la_reduce(
    const float* __restrict__ pkv, const float* __restrict__ pks,
    unsigned short* __restrict__ kvt, float* __restrict__ ksum)
{
    const int b = blockIdx.x, nh = b >> 4, sl = b & 15;
    const int e = sl * 256 + threadIdx.x;          // e = d*64 + m
    const float* src = pkv + (size_t)nh * SPLIT_ * (E_ * E_) + e;
    float s = 0.f;
    #pragma unroll
    for (int c = 0; c < SPLIT_; ++c) s += src[(size_t)c * (E_ * E_)];
    const int d = e >> 6, m = e & 63;
    kvt[(size_t)nh * (E_ * E_) + m * E_ + d] = f2bf(s);

    if (sl == 0 && threadIdx.x < E_) {
        const float* sp = pks + (size_t)nh * SPLIT_ * E_ + threadIdx.x;
        float ss = 0.f;
        #pragma unroll
        for (int c = 0; c < SPLIT_; ++c) ss += sp[c * E_];
        ksum[nh * E_ + threadIdx.x] = ss;
    }
}

// ---------------------------------------------------------------------------
// Phase 2: out[l][m] = z[l] * sum_d qf[l,d]*KV[d,m] via MFMA.
// 1024 blocks x 4 waves x 2 bands of 32 rows. A-frags (featmapped q, bf16)
// built in registers straight from global; B-frags + ksum register-resident.
// zdenom in fp32 VALU + 1 shfl; z broadcast via 128 B LDS.
// ---------------------------------------------------------------------------
__global__ __launch_bounds__(256) void la_out(
    const float* __restrict__ q, const unsigned short* __restrict__ kvt,
    const float* __restrict__ ksum, float* __restrict__ out)
{
    const int blk = blockIdx.x, nh = blk >> 5, tile = blk & 31;
    const int n = nh / H_, h = nh % H_;
    const int t = threadIdx.x, l = t & 63, w = t >> 6;
    const int lm = l & 31, lh = l >> 5;

    __shared__ float zbuf[4][32];

    const unsigned short* kb = kvt + (size_t)nh * (E_ * E_);
    const float* ks = ksum + nh * E_;

    bf16x8 bfr[4][2];
    float4 kr[4][2];
    #pragma unroll
    for (int st = 0; st < 4; ++st) {
        #pragma unroll
        for (int c = 0; c < 2; ++c)
            bfr[st][c] = *(const bf16x8*)&kb[(32 * c + lm) * E_ + st * 16 + 8 * lh];
        kr[st][0] = *(const float4*)&ks[st * 16 + 8 * lh];
        kr[st][1] = *(const float4*)&ks[st * 16 + 8 * lh + 4];
    }

    const size_t base = (size_t)n * (L_ * H_ * E_) + (size_t)h * E_;

    #pragma unroll
    for (int bnd = 0; bnd < 2; ++bnd) {
        const int l0 = tile * 256 + w * 64 + bnd * 32;
        const float* qp = q + base + (size_t)(l0 + lm) * STRIDE_ + 8 * lh;

        float4 qa[4], qb[4];
        #pragma unroll
        for (int st = 0; st < 4; ++st) {
            qa[st] = *(const float4*)(qp + st * 16);
            qb[st] = *(const float4*)(qp + st * 16 + 4);
        }

        float zd = 0.f;
        bf16x8 af[4];
        #pragma unroll
        for (int st = 0; st < 4; ++st) {
            const float f0 = featmap(qa[st].x), f1 = featmap(qa[st].y),
                        f2 = featmap(qa[st].z), f3 = featmap(qa[st].w);
            const float g0 = featmap(qb[st].x), g1 = featmap(qb[st].y),
                        g2 = featmap(qb[st].z), g3 = featmap(qb[st].w);
            zd += f0 * kr[st][0].x + f1 * kr[st][0].y + f2 * kr[st][0].z + f3 * kr[st][0].w
                + g0 * kr[st][1].x + g1 * kr[st][1].y + g2 * kr[st][1].z + g3 * kr[st][1].w;
            bf16x8 a;
            a[0] = (short)f2bf(f0); a[1] = (short)f2bf(f1);
            a[2] = (short)f2bf(f2); a[3] = (short)f2bf(f3);
            a[4] = (short)f2bf(g0); a[5] = (short)f2bf(g1);
            a[6] = (short)f2bf(g2); a[7] = (short)f2bf(g3);
            af[st] = a;
        }
        zd += __shfl_xor(zd, 32);
        const float z = 1.0f / (zd + 1e-6f);
        if (l < 32) zbuf[w][l] = z;
        __builtin_amdgcn_wave_barrier();

        f32x16 c0 = {0,0,0,0,0,0,0,0,0,0,0,0,0,0,0,0};
        f32x16 c1 = {0,0,0,0,0,0,0,0,0,0,0,0,0,0,0,0};
        #pragma unroll
        for (int st = 0; st < 4; ++st) {
            c0 = __builtin_amdgcn_mfma_f32_32x32x16_bf16(af[st], bfr[st][0], c0, 0, 0, 0);
            c1 = __builtin_amdgcn_mfma_f32_32x32x16_bf16(af[st], bfr[st][1], c1, 0, 0, 0);
        }

        float* op = out + base + (size_t)l0 * STRIDE_ + lm;
        #pragma unroll
        for (int r = 0; r < 16; ++r) {
            const int ro = (r & 3) + 8 * (r >> 2) + 4 * lh;
            const float zz = zbuf[w][ro];
            op[(size_t)ro * STRIDE_]      = c0[r] * zz;
            op[(size_t)ro * STRIDE_ + 32] = c1[r] * zz;
        }
        __builtin_amdgcn_wave_barrier();   // zbuf reused next band
    }
}

extern "C" void kernel_launch(void* const* d_in, const int* in_sizes, int n_in,
                              void* d_out, int out_size, void* d_ws, size_t ws_size,
                              hipStream_t stream) {
    (void)in_sizes; (void)n_in; (void)out_size; (void)ws_size;
    const float* qq = (const float*)d_in[0];
    const float* kk = (const float*)d_in[1];
    const float* vv = (const float*)d_in[2];
    float* outp = (float*)d_out;
    float* ws   = (float*)d_ws;

    float* pkv = ws;
    float* pks = ws + PKS_OFF;
    unsigned short* kvt = (unsigned short*)(ws + KVT_OFF);
    float* ksm = ws + KSUM_OFF;

    la_kv<<<NH_ * SPLIT_, 256, 0, stream>>>(kk, vv, pkv, pks);
    la_reduce<<<NH_ * 16, 256, 0, stream>>>(pkv, pks, kvt, ksm);
    la_out<<<NH_ * 32, 256, 0, stream>>>(qq, kvt, ksm, outp);
}